// Round 3
// baseline (133.487 us; speedup 1.0000x reference)
//
#include <hip/hip_runtime.h>
#include <hip/hip_bf16.h>
#include <math.h>

#define EMBED 768
#define NTOK  4096
#define NB    4
#define ROWS  16384          // 4 * 4096
#define CN    192            // Q(64)|K(64)|V(64)

typedef __attribute__((ext_vector_type(8))) short bf16x8;          // 8 bf16 = 4 VGPR
typedef __attribute__((ext_vector_type(8))) unsigned short u16x8;  // store vector
typedef __attribute__((ext_vector_type(4))) float f32x4;           // MFMA acc

// Split fp32 into h + l bf16 (RNE both, tie-parity exact): used in wprep.
__device__ inline void split2(float f, short& h, short& l) {
  union { float f; unsigned u; } a; a.f = f;
  unsigned r = (a.u + 0x7FFFu + ((a.u >> 16) & 1u)) & 0xFFFF0000u;
  h = (short)(r >> 16);
  union { unsigned u; float f; } hf; hf.u = r;
  union { float f; unsigned u; } b; b.f = f - hf.f;
  l = (short)((b.u + 0x7FFFu + ((b.u >> 16) & 1u)) >> 16);
}

// ---------------------------------------------------------------------------
// W prep: LDS-staged transpose, coalesced both sides.
// NEW layout (conflict-free ds_read in qkv):
//   Wt[ks][plane][q][n][j] bf16, elem = ks*12288 + p*6144 + q*1536 + n*8 + j
//   where k = ks*32 + q*8 + j, n in [0,192).
// Per-ks slice (24576 B) is verbatim the LDS staging block for qkv.
// Also zeroes Vsum.
// ---------------------------------------------------------------------------
__global__ __launch_bounds__(256) void wprep(const float* __restrict__ Wq,
                                             const float* __restrict__ Wk,
                                             const float* __restrict__ Wv,
                                             unsigned short* __restrict__ Wt,
                                             float* __restrict__ Vsum) {
  __shared__ float tile[32 * 64];   // W[ks*32 .. +32][0..64]
  const int b   = blockIdx.x;
  const int mat = b / 24;           // 0=Wq 1=Wk 2=Wv
  const int ks  = b - mat * 24;
  const float* W = (mat == 0) ? Wq : (mat == 1) ? Wk : Wv;
  const int t = threadIdx.x;

  const float4* src = (const float4*)(W + ks * 2048);
  ((float4*)tile)[t]       = src[t];
  ((float4*)tile)[t + 256] = src[t + 256];
  __syncthreads();

  const int q    = t >> 6;          // k-oct 0..3
  const int nloc = t & 63;          // 0..63 within this matrix
  u16x8 hv, lv;
#pragma unroll
  for (int j = 0; j < 8; ++j) {
    short h, l;
    split2(tile[(q * 8 + j) * 64 + nloc], h, l);
    hv[j] = (unsigned short)h;
    lv[j] = (unsigned short)l;
  }
  const size_t base = (size_t)ks * 12288 + (size_t)q * 1536 + (size_t)(mat * 64 + nloc) * 8;
  *(u16x8*)(Wt + base)        = hv;
  *(u16x8*)(Wt + base + 6144) = lv;

  if (b == 0 && t < NB * 64) Vsum[t] = 0.f;
}

// ---------------------------------------------------------------------------
// MFMA GEMM: C[16384][192] = x @ W + bias, split-bf16 (3 MFMA passes).
// 512 blocks x 256 threads = 4 waves, each an n-slice (48 cols), m_t=2
// (wave tile 32x48, block tile 32x192). B staged global->LDS (verbatim
// 24576-B slice, double buffered, 1 barrier per k-step). Conflict-free
// ds_read_b128 (quarter-wave reads 16 consecutive 16B slots). HW-RNE
// split for A (v_cvt_pk_bf16_f32). Fused Vsum epilogue.
// ---------------------------------------------------------------------------
__device__ inline void gload_lds16(const unsigned short* g, unsigned short* l) {
  __builtin_amdgcn_global_load_lds(
      (const __attribute__((address_space(1))) unsigned int*)(g),
      (__attribute__((address_space(3))) unsigned int*)(l),
      16, 0, 0);
}

#define STAGE(LB, KS) do {                                            \
    const unsigned short* _g = Wtu + (size_t)(KS) * 12288 + tid * 8;  \
    unsigned short* _l = (LB) + tid * 8;                              \
    gload_lds16(_g,          _l);                                     \
    gload_lds16(_g + 2048,   _l + 2048);                              \
    gload_lds16(_g + 4096,   _l + 4096);                              \
    gload_lds16(_g + 6144,   _l + 6144);                              \
    gload_lds16(_g + 8192,   _l + 8192);                              \
    gload_lds16(_g + 10240,  _l + 10240);                             \
  } while (0)

// HW RNE split: f = h + l with both planes RNE (v_cvt_pk_bf16_f32 on gfx950).
__device__ inline void splitHW(float f, short& h, short& l) {
  __hip_bfloat16 hb = __float2bfloat16(f);
  float hf = __bfloat162float(hb);
  __hip_bfloat16 lb = __float2bfloat16(f - hf);
  h = __builtin_bit_cast(short, hb);
  l = __builtin_bit_cast(short, lb);
}

__device__ inline void cvt8hw(const float4 f0, const float4 f1, bf16x8& h, bf16x8& l) {
  short hh, ll;
  splitHW(f0.x, hh, ll); h[0] = hh; l[0] = ll;
  splitHW(f0.y, hh, ll); h[1] = hh; l[1] = ll;
  splitHW(f0.z, hh, ll); h[2] = hh; l[2] = ll;
  splitHW(f0.w, hh, ll); h[3] = hh; l[3] = ll;
  splitHW(f1.x, hh, ll); h[4] = hh; l[4] = ll;
  splitHW(f1.y, hh, ll); h[5] = hh; l[5] = ll;
  splitHW(f1.z, hh, ll); h[6] = hh; l[6] = ll;
  splitHW(f1.w, hh, ll); h[7] = hh; l[7] = ll;
}

#define DO_NT3(LBP, NT, ACC0, ACC1) do {                                       \
    bf16x8 _bh = *(const bf16x8*)((LBP) + (NT) * 128);                         \
    bf16x8 _bl = *(const bf16x8*)((LBP) + (NT) * 128 + 6144);                  \
    ACC0 = __builtin_amdgcn_mfma_f32_16x16x32_bf16(ah0, _bh, ACC0, 0, 0, 0);   \
    ACC0 = __builtin_amdgcn_mfma_f32_16x16x32_bf16(ah0, _bl, ACC0, 0, 0, 0);   \
    ACC0 = __builtin_amdgcn_mfma_f32_16x16x32_bf16(al0, _bh, ACC0, 0, 0, 0);   \
    ACC1 = __builtin_amdgcn_mfma_f32_16x16x32_bf16(ah1, _bh, ACC1, 0, 0, 0);   \
    ACC1 = __builtin_amdgcn_mfma_f32_16x16x32_bf16(ah1, _bl, ACC1, 0, 0, 0);   \
    ACC1 = __builtin_amdgcn_mfma_f32_16x16x32_bf16(al1, _bh, ACC1, 0, 0, 0);   \
  } while (0)

#define COMPUTE(LB, A00, A01, A10, A11) do {                          \
    bf16x8 ah0, al0, ah1, al1;                                        \
    cvt8hw(A00, A01, ah0, al0);                                       \
    cvt8hw(A10, A11, ah1, al1);                                       \
    const unsigned short* _lb = (LB) + lbo;                           \
    DO_NT3(_lb, 0, acc00, acc10);                                     \
    DO_NT3(_lb, 1, acc01, acc11);                                     \
    DO_NT3(_lb, 2, acc02, acc12);                                     \
  } while (0)

__global__ __launch_bounds__(256, 2) void qkv_mfma(const float* __restrict__ x,
                                                   const unsigned short* __restrict__ Wtu,
                                                   const float* __restrict__ bq,
                                                   const float* __restrict__ bk,
                                                   const float* __restrict__ bv,
                                                   float* __restrict__ C,
                                                   float* __restrict__ Vsum) {
  __shared__ unsigned short lbuf0[12288];   // 24576 B, ks even
  __shared__ unsigned short lbuf1[12288];   // 24576 B, ks odd

  const int tid  = threadIdx.x;
  const int lane = tid & 63;
  const int wn   = tid >> 6;          // n-slice 0..3 (48 cols each)
  const int ml   = lane & 15;
  const int q    = lane >> 4;         // k-oct
  const int r0   = blockIdx.x * 32;
  // LDS frag base (shorts): [q][n] with n = wn*48 + nt*16 + ml; nt adds 128.
  const int lbo  = q * 1536 + (wn * 48 + ml) * 8;

  f32x4 acc00 = {0.f,0.f,0.f,0.f}, acc01 = {0.f,0.f,0.f,0.f}, acc02 = {0.f,0.f,0.f,0.f};
  f32x4 acc10 = {0.f,0.f,0.f,0.f}, acc11 = {0.f,0.f,0.f,0.f}, acc12 = {0.f,0.f,0.f,0.f};

  const float* xa0 = x + (size_t)(r0 + ml) * EMBED + q * 8;        // m-frag 0
  const float* xa1 = xa0 + (size_t)16 * EMBED;                     // m-frag 1

  // prologue
  STAGE(lbuf0, 0);
  float4 a00 = *(const float4*)xa0;
  float4 a01 = *(const float4*)(xa0 + 4);
  float4 a10 = *(const float4*)xa1;
  float4 a11 = *(const float4*)(xa1 + 4);

  for (int ks = 0; ks < 24; ks += 2) {
    // ---- even step: compute lbuf0, stage ks+1 -> lbuf1 ----
    __syncthreads();                       // staging of lbuf0 drained
    STAGE(lbuf1, ks + 1);
    float4 n00 = *(const float4*)(xa0 + 32);
    float4 n01 = *(const float4*)(xa0 + 36);
    float4 n10 = *(const float4*)(xa1 + 32);
    float4 n11 = *(const float4*)(xa1 + 36);
    COMPUTE(lbuf0, a00, a01, a10, a11);

    // ---- odd step: compute lbuf1, stage ks+2 -> lbuf0 ----
    __syncthreads();
    if (ks < 22) {
      STAGE(lbuf0, ks + 2);
      a00 = *(const float4*)(xa0 + 64);
      a01 = *(const float4*)(xa0 + 68);
      a10 = *(const float4*)(xa1 + 64);
      a11 = *(const float4*)(xa1 + 68);
    }
    COMPUTE(lbuf1, n00, n01, n10, n11);
    xa0 += 64; xa1 += 64;
  }

  // epilogue: bias + store. C/D layout: col = ml, row = q*4 + reg.
#define EPI(NT, ACC, MF) do {                                               \
    const int n = wn * 48 + (NT) * 16 + ml;                                 \
    const float bias = (n < 64) ? bq[n] : (n < 128) ? bk[n - 64] : bv[n - 128]; \
    const int row = r0 + (MF) * 16 + q * 4;                                 \
    C[(size_t)(row + 0) * CN + n] = ACC[0] + bias;                          \
    C[(size_t)(row + 1) * CN + n] = ACC[1] + bias;                          \
    C[(size_t)(row + 2) * CN + n] = ACC[2] + bias;                          \
    C[(size_t)(row + 3) * CN + n] = ACC[3] + bias;                          \
  } while (0)

  EPI(0, acc00, 0); EPI(1, acc01, 0); EPI(2, acc02, 0);
  EPI(0, acc10, 1); EPI(1, acc11, 1); EPI(2, acc12, 1);

  // fused Vsum partials: V cols are n >= 128 (wn==2 nt==2, wn==3 all nt).
  // Per col: sum 8 rows locally (2 m-frags x 4 regs) + 8*bias, shfl over the
  // 4 q-groups (-> 32 rows), one atomic per col per block.
#define VS(NT, ACC0, ACC1) do {                                             \
    const int n = wn * 48 + (NT) * 16 + ml;                                 \
    if (n >= 128) {                                                         \
      float s = ACC0[0] + ACC0[1] + ACC0[2] + ACC0[3]                       \
              + ACC1[0] + ACC1[1] + ACC1[2] + ACC1[3] + 8.f * bv[n - 128];  \
      s += __shfl_xor(s, 16, 64);                                           \
      s += __shfl_xor(s, 32, 64);                                           \
      if (q == 0) atomicAdd(&Vsum[(r0 >> 12) * 64 + (n - 128)], s);         \
    }                                                                       \
  } while (0)

  VS(0, acc00, acc10); VS(1, acc01, acc11); VS(2, acc02, acc12);
}

// ---------------------------------------------------------------------------
// Per-row scores + softmax-with-zero-background + V combine (faithful quirk).
// ---------------------------------------------------------------------------
__global__ __launch_bounds__(256) void attn_kernel(const float* __restrict__ C,
                                                   const float* __restrict__ Vsum,
                                                   float* __restrict__ out) {
  const int t    = threadIdx.x;
  const int lane = t & 63;
  const int wave = t >> 6;
  const int r = blockIdx.x * 4 + wave;
  const int b = r >> 12;
  const int i = r & (NTOK - 1);

  const float q  = C[(size_t)r * CN + lane];
  const float kc = C[(size_t)r * CN + 64 + lane];
  float km = 0.f, kp = 0.f;
  if (i > 0)        km = C[(size_t)(r - 1) * CN + 64 + lane];
  if (i < NTOK - 1) kp = C[(size_t)(r + 1) * CN + 64 + lane];

  float p0 = q * km, p1 = q * kc, p2 = q * kp;
#pragma unroll
  for (int off = 32; off > 0; off >>= 1) {
    p0 += __shfl_xor(p0, off, 64);
    p1 += __shfl_xor(p1, off, 64);
    p2 += __shfl_xor(p2, off, 64);
  }

  const float s0 = (i > 0) ? p0 : 0.f;
  const float s1 = p1;
  const float s2 = (i < NTOK - 1) ? p2 : 0.f;
  const float m  = fmaxf(fmaxf(s0, s1), fmaxf(s2, 0.f));
  const float e0 = expf(s0 - m);
  const float e1 = expf(s1 - m);
  const float e2 = expf(s2 - m);
  const float ez = expf(-m);
  const float Z  = e0 + e1 + e2 + (float)(NTOK - 3) * ez;

  const size_t vb = ((size_t)b * NTOK) * CN + 128;
  const float v0 = C[vb + lane];
  const float v1 = C[vb + CN + lane];
  const float v2 = C[vb + 2 * (size_t)CN + lane];
  const float vs = Vsum[b * 64 + lane];

  out[(size_t)r * 64 + lane] =
      (e0 * v0 + e1 * v1 + e2 * v2 + ez * (vs - v0 - v1 - v2)) / Z;
}

// ---------------------------------------------------------------------------
extern "C" void kernel_launch(void* const* d_in, const int* in_sizes, int n_in,
                              void* d_out, int out_size, void* d_ws, size_t ws_size,
                              hipStream_t stream) {
  const float* x  = (const float*)d_in[0];
  const float* Wq = (const float*)d_in[1];
  const float* bq = (const float*)d_in[2];
  const float* Wk = (const float*)d_in[3];
  const float* bk = (const float*)d_in[4];
  const float* Wv = (const float*)d_in[5];
  const float* bv = (const float*)d_in[6];
  float* out = (float*)d_out;

  float* C    = (float*)d_ws;                              // 16384 x 192 fp32 (12 MiB)
  float* Vsum = C + (size_t)ROWS * CN;                     // 4 x 64
  unsigned short* Wt = (unsigned short*)(Vsum + NB * 64);  // 24 x 2 x 192 x 32 bf16 (576 KiB)

  wprep<<<72, 256, 0, stream>>>(Wq, Wk, Wv, Wt, Vsum);
  qkv_mfma<<<512, 256, 0, stream>>>(x, Wt, bq, bk, bv, C, Vsum);
  attn_kernel<<<ROWS / 4, 256, 0, stream>>>(C, Vsum, out);
}